// Round 1
// baseline (788.045 us; speedup 1.0000x reference)
//
#include <hip/hip_runtime.h>
#include <stdint.h>

#define H_ 128
#define W_ 128
#define HW_ 16384
#define B_ 2

typedef __attribute__((ext_vector_type(4))) float f32x4;
typedef _Float16 half_t;
typedef __attribute__((ext_vector_type(8))) _Float16 h8v;
typedef __attribute__((ext_vector_type(4))) _Float16 h4v;

__device__ __forceinline__ f32x4 MFMA(h8v a, h8v b, f32x4 c) {
  return __builtin_amdgcn_mfma_f32_16x16x32_f16(a, b, c, 0, 0, 0);
}
__device__ __forceinline__ f32x4 zero4() {
  f32x4 z; z[0] = 0.f; z[1] = 0.f; z[2] = 0.f; z[3] = 0.f; return z;
}
// Swizzled LDS offset (element units). Tiles are [rows][64] fp16 (128B rows).
// XOR the 16B-chunk index with row&7 -> conflict-free ds_read_b128 (G4).
__device__ __forceinline__ int swz(int r, int c8) {
  return r * 64 + ((c8 ^ (r & 7)) << 3);
}

// ---------- pack: three fp32 NCHW (B,256,H,W) -> one fp16 NHWC (B,H,W,768) ----------
__global__ __launch_bounds__(256) void pack_x(
    const float* __restrict__ f1, const float* __restrict__ f2,
    const float* __restrict__ f3, half_t* __restrict__ xcat) {
  __shared__ float tile[64][65];
  int bid = blockIdx.x;
  int t = bid % 24, by = bid / 24;      // by = b*H + y
  int b = by >> 7, y = by & 127;
  int s = t / 8, t2 = t % 8;
  int x0 = (t2 & 1) * 64, c0 = (t2 >> 1) * 64;
  const float* f = (s == 0) ? f1 : ((s == 1) ? f2 : f3);
  int tid = threadIdx.x;
  int rx = tid & 63, rc = tid >> 6;
  const float* srcp = f + ((size_t)(b * 256 + c0)) * HW_ + (size_t)y * W_ + x0;
#pragma unroll
  for (int i = 0; i < 16; ++i) {
    int c = rc + i * 4;
    tile[c][rx] = srcp[(size_t)c * HW_ + rx];
  }
  __syncthreads();
  size_t pixrow = (size_t)(b * H_ + y) * W_;
#pragma unroll
  for (int it = 0; it < 2; ++it) {
    int task = tid + it * 256;
    int x = task & 63, c8 = task >> 6;
    h8v v;
#pragma unroll
    for (int j = 0; j < 8; ++j) v[j] = (half_t)tile[c8 * 8 + j][x];
    *(h8v*)(xcat + (pixrow + x0 + x) * 768 + s * 256 + c0 + c8 * 8) = v;
  }
}

// ---------- weight transform: OIHW fp32 -> [COPAD][9*CI] fp16, k = tap*CI+ci ----------
__global__ __launch_bounds__(256) void wtrans(
    const float* __restrict__ w, half_t* __restrict__ wt,
    int CO, int COPAD, int CI) {
  int idx = blockIdx.x * 256 + threadIdx.x;
  int K = 9 * CI;
  if (idx >= COPAD * K) return;
  int co = idx / K, k = idx % K;
  int t = k / CI, ci = k % CI;
  float v = (co < CO) ? w[((size_t)co * CI + ci) * 9 + t] : 0.f;
  wt[idx] = (half_t)v;
}

__global__ __launch_bounds__(256) void castcopy(
    const float* __restrict__ w, half_t* __restrict__ o, int n) {
  int i = blockIdx.x * 256 + threadIdx.x;
  if (i < n) o[i] = (half_t)w[i];
}

// ---------- generic 3x3 conv, implicit GEMM, NHWC fp16 ----------
// Operand-swapped: A = weights [co][k] (rows), B = activations [px][k] (cols).
// Block: 64 co x 128 px (one image row). 4 waves, each 64co x 32px.
template <int CIN, bool RELU, bool FP32OUT>
__global__ __launch_bounds__(256) void conv3x3(
    const half_t* __restrict__ in, const half_t* __restrict__ wt,
    const float* __restrict__ bias, half_t* __restrict__ outb,
    float* __restrict__ outf, int COUT) {
  __shared__ __align__(16) half_t wl[64 * 64];
  __shared__ __align__(16) half_t al[128 * 64];
  int tid = threadIdx.x;
  int by = blockIdx.x;                  // b*H + y
  int b = by >> 7, y = by & 127;
  int co0 = blockIdx.y * 64;
  int w = tid >> 6, l = tid & 63;
  int lr = l & 15, lg = l >> 4;
  size_t rowpix = (size_t)by * W_;
  f32x4 acc[4][2];
#pragma unroll
  for (int i = 0; i < 4; ++i)
#pragma unroll
    for (int j = 0; j < 2; ++j) acc[i][j] = zero4();

  const int KSTEPS = CIN / 64;
  for (int t = 0; t < 9; ++t) {
    int sy = y + (t / 3) - 1;
    int kxo = (t % 3) - 1;
    bool yok = (sy >= 0) && (sy < H_);
    for (int cs = 0; cs < KSTEPS; ++cs) {
      int c0 = cs * 64;
      __syncthreads();
      // stage weights: 64 rows x 8 chunks of 8
      {
        const half_t* wp = wt + (size_t)co0 * (9 * CIN) + t * CIN + c0;
#pragma unroll
        for (int it = 0; it < 2; ++it) {
          int task = tid + it * 256;
          int r = task >> 3, c8 = task & 7;
          *(h8v*)(wl + swz(r, c8)) = *(const h8v*)(wp + (size_t)r * (9 * CIN) + c8 * 8);
        }
      }
      // stage activations: 128 px x 8 chunks (zero-pad at borders)
      {
#pragma unroll
        for (int it = 0; it < 4; ++it) {
          int task = tid + it * 256;
          int px = task >> 3, c8 = task & 7;
          int sx = px + kxo;
          h8v v;
          if (yok && sx >= 0 && sx < W_) {
            v = *(const h8v*)(in + ((size_t)(b * H_ + sy) * W_ + sx) * CIN + c0 + c8 * 8);
          } else {
#pragma unroll
            for (int j = 0; j < 8; ++j) v[j] = (half_t)0.f;
          }
          *(h8v*)(al + swz(px, c8)) = v;
        }
      }
      __syncthreads();
      // compute
      h8v af[4][2], bf[2][2];
#pragma unroll
      for (int cg = 0; cg < 4; ++cg)
#pragma unroll
        for (int kc = 0; kc < 2; ++kc)
          af[cg][kc] = *(const h8v*)(wl + swz(16 * cg + lr, 4 * kc + lg));
#pragma unroll
      for (int pg = 0; pg < 2; ++pg)
#pragma unroll
        for (int kc = 0; kc < 2; ++kc)
          bf[pg][kc] = *(const h8v*)(al + swz(32 * w + 16 * pg + lr, 4 * kc + lg));
#pragma unroll
      for (int cg = 0; cg < 4; ++cg)
#pragma unroll
        for (int pg = 0; pg < 2; ++pg) {
          acc[cg][pg] = MFMA(af[cg][0], bf[pg][0], acc[cg][pg]);
          acc[cg][pg] = MFMA(af[cg][1], bf[pg][1], acc[cg][pg]);
        }
    }
  }
  // epilogue: D row = co (4 consecutive per lane), col = px
#pragma unroll
  for (int cg = 0; cg < 4; ++cg) {
    int co = co0 + 16 * cg + 4 * lg;
    if (FP32OUT && co >= COUT) continue;
    f32x4 bv = *(const f32x4*)(bias + co);
#pragma unroll
    for (int pg = 0; pg < 2; ++pg) {
      size_t pix = rowpix + 32 * w + 16 * pg + lr;
      f32x4 v = acc[cg][pg];
#pragma unroll
      for (int r = 0; r < 4; ++r) {
        v[r] += bv[r];
        if (RELU) v[r] = fmaxf(v[r], 0.f);
      }
      if (FP32OUT) {
        *(f32x4*)(outf + pix * COUT + co) = v;
      } else {
        h4v pv;
#pragma unroll
        for (int r = 0; r < 4; ++r) pv[r] = (half_t)v[r];
        *(h4v*)(outb + pix * COUT + co) = pv;
      }
    }
  }
}

// ---------- deformable conv: bilinear sampling fused into implicit GEMM ----------
// out[px][co] = sum_{t,ci} samp(px,t,ci) * wd[co][t*256+ci]
__global__ __launch_bounds__(256) void dcn(
    const half_t* __restrict__ xcat, int cbase,
    const float* __restrict__ off, int obase,
    const half_t* __restrict__ wt, half_t* __restrict__ outb) {
  __shared__ __align__(16) half_t wl[64 * 64];
  __shared__ __align__(16) half_t al[128 * 64];
  __shared__ int caddr[128][4];
  __shared__ float cwt[128][4];
  int tid = threadIdx.x;
  int by = blockIdx.x;
  int b = by >> 7, y = by & 127;
  int co0 = blockIdx.y * 64;
  int w = tid >> 6, l = tid & 63;
  int lr = l & 15, lg = l >> 4;
  size_t rowpix = (size_t)by * W_;
  f32x4 acc[4][2];
#pragma unroll
  for (int i = 0; i < 4; ++i)
#pragma unroll
    for (int j = 0; j < 2; ++j) acc[i][j] = zero4();

  for (int t = 0; t < 9; ++t) {
    // per-tap bilinear coefficients (threads 0..127, one per pixel of the row)
    if (tid < 128) {
      int px = tid;
      const float* op = off + (rowpix + px) * 36 + obase + 2 * t;
      float dy = op[0], dx = op[1];
      float ysf = (float)(y + (t / 3) - 1) + dy;
      float xsf = (float)(px + (t % 3) - 1) + dx;
      float y0f = floorf(ysf), x0f = floorf(xsf);
      float fy = ysf - y0f, fx = xsf - x0f;
      int y0 = (int)y0f, x0 = (int)x0f;
#pragma unroll
      for (int c = 0; c < 4; ++c) {
        int iy = y0 + (c >> 1), ix = x0 + (c & 1);
        float wc = ((c >> 1) ? fy : 1.f - fy) * ((c & 1) ? fx : 1.f - fx);
        bool valid = (iy >= 0) && (iy < H_) && (ix >= 0) && (ix < W_);
        int cy = iy < 0 ? 0 : (iy > H_ - 1 ? H_ - 1 : iy);
        int cx = ix < 0 ? 0 : (ix > W_ - 1 ? W_ - 1 : ix);
        caddr[px][c] = ((b * H_ + cy) * W_ + cx) * 768 + cbase;
        cwt[px][c] = valid ? wc : 0.f;
      }
    }
    for (int cs = 0; cs < 4; ++cs) {
      int c0 = cs * 64;
      __syncthreads();  // also orders coeff writes (cs==0) vs reads below
      // stage weights
      {
        const half_t* wp = wt + (size_t)co0 * 2304 + t * 256 + c0;
#pragma unroll
        for (int it = 0; it < 2; ++it) {
          int task = tid + it * 256;
          int r = task >> 3, c8 = task & 7;
          *(h8v*)(wl + swz(r, c8)) = *(const h8v*)(wp + (size_t)r * 2304 + c8 * 8);
        }
      }
      // stage sampled activations: bilinear over 4 corners, 8 channels/task
      {
#pragma unroll
        for (int it = 0; it < 4; ++it) {
          int task = tid + it * 256;
          int px = task >> 3, c8 = task & 7;
          int cc = c0 + c8 * 8;
          float av[8];
#pragma unroll
          for (int j = 0; j < 8; ++j) av[j] = 0.f;
#pragma unroll
          for (int c = 0; c < 4; ++c) {
            float wc = cwt[px][c];
            h8v v = *(const h8v*)(xcat + caddr[px][c] + cc);
#pragma unroll
            for (int j = 0; j < 8; ++j) av[j] += wc * (float)v[j];
          }
          h8v pv;
#pragma unroll
          for (int j = 0; j < 8; ++j) pv[j] = (half_t)av[j];
          *(h8v*)(al + swz(px, c8)) = pv;
        }
      }
      __syncthreads();
      h8v af[4][2], bf[2][2];
#pragma unroll
      for (int cg = 0; cg < 4; ++cg)
#pragma unroll
        for (int kc = 0; kc < 2; ++kc)
          af[cg][kc] = *(const h8v*)(wl + swz(16 * cg + lr, 4 * kc + lg));
#pragma unroll
      for (int pg = 0; pg < 2; ++pg)
#pragma unroll
        for (int kc = 0; kc < 2; ++kc)
          bf[pg][kc] = *(const h8v*)(al + swz(32 * w + 16 * pg + lr, 4 * kc + lg));
#pragma unroll
      for (int cg = 0; cg < 4; ++cg)
#pragma unroll
        for (int pg = 0; pg < 2; ++pg) {
          acc[cg][pg] = MFMA(af[cg][0], bf[pg][0], acc[cg][pg]);
          acc[cg][pg] = MFMA(af[cg][1], bf[pg][1], acc[cg][pg]);
        }
    }
  }
#pragma unroll
  for (int cg = 0; cg < 4; ++cg) {
    int co = co0 + 16 * cg + 4 * lg;
#pragma unroll
    for (int pg = 0; pg < 2; ++pg) {
      size_t pix = rowpix + 32 * w + 16 * pg + lr;
      f32x4 v = acc[cg][pg];
      h4v pv;
#pragma unroll
      for (int r = 0; r < 4; ++r) pv[r] = (half_t)v[r];
      *(h4v*)(outb + pix * 256 + co) = pv;
    }
  }
}

// ---------- 1x1 fuse conv: out fp32 NCHW. Unswapped (A=act rows -> contiguous px stores) ----------
__global__ __launch_bounds__(256) void fuse1x1(
    const half_t* __restrict__ xcat, const half_t* __restrict__ al2,
    const half_t* __restrict__ al3, const half_t* __restrict__ wt,
    const float* __restrict__ bias, float* __restrict__ out) {
  __shared__ __align__(16) half_t wl[64 * 64];
  __shared__ __align__(16) half_t al[128 * 64];
  int tid = threadIdx.x;
  int by = blockIdx.x;
  int b = by >> 7, y = by & 127;
  int co0 = blockIdx.y * 64;
  int w = tid >> 6, l = tid & 63;
  int lr = l & 15, lg = l >> 4;
  size_t rowpix = (size_t)by * W_;
  f32x4 acc[2][4];  // [pg][cg]
#pragma unroll
  for (int i = 0; i < 2; ++i)
#pragma unroll
    for (int j = 0; j < 4; ++j) acc[i][j] = zero4();

  for (int cs = 0; cs < 12; ++cs) {
    __syncthreads();
    {
      const half_t* wp = wt + (size_t)co0 * 768 + cs * 64;
#pragma unroll
      for (int it = 0; it < 2; ++it) {
        int task = tid + it * 256;
        int r = task >> 3, c8 = task & 7;
        *(h8v*)(wl + swz(r, c8)) = *(const h8v*)(wp + (size_t)r * 768 + c8 * 8);
      }
    }
    {
#pragma unroll
      for (int it = 0; it < 4; ++it) {
        int task = tid + it * 256;
        int px = task >> 3, c8 = task & 7;
        int kk = cs * 64 + c8 * 8;
        size_t pix = rowpix + px;
        const half_t* sp;
        if (kk < 256) sp = xcat + pix * 768 + kk;
        else if (kk < 512) sp = al2 + pix * 256 + (kk - 256);
        else sp = al3 + pix * 256 + (kk - 512);
        *(h8v*)(al + swz(px, c8)) = *(const h8v*)sp;
      }
    }
    __syncthreads();
    h8v af[2][2], bfr[4][2];
#pragma unroll
    for (int pg = 0; pg < 2; ++pg)
#pragma unroll
      for (int kc = 0; kc < 2; ++kc)
        af[pg][kc] = *(const h8v*)(al + swz(32 * w + 16 * pg + lr, 4 * kc + lg));
#pragma unroll
    for (int cg = 0; cg < 4; ++cg)
#pragma unroll
      for (int kc = 0; kc < 2; ++kc)
        bfr[cg][kc] = *(const h8v*)(wl + swz(16 * cg + lr, 4 * kc + lg));
#pragma unroll
    for (int pg = 0; pg < 2; ++pg)
#pragma unroll
      for (int cg = 0; cg < 4; ++cg) {
        acc[pg][cg] = MFMA(af[pg][0], bfr[cg][0], acc[pg][cg]);
        acc[pg][cg] = MFMA(af[pg][1], bfr[cg][1], acc[pg][cg]);
      }
  }
  // D row = px (4 consecutive per lane -> float4 NCHW store), col = co
#pragma unroll
  for (int pg = 0; pg < 2; ++pg)
#pragma unroll
    for (int cg = 0; cg < 4; ++cg) {
      int px = 32 * w + 16 * pg + 4 * lg;
      int co = co0 + 16 * cg + lr;
      float bb = bias[co];
      f32x4 v = acc[pg][cg];
#pragma unroll
      for (int r = 0; r < 4; ++r) v[r] += bb;
      *(f32x4*)(out + ((size_t)(b * 256 + co)) * HW_ + (size_t)y * W_ + px) = v;
    }
}

extern "C" void kernel_launch(void* const* d_in, const int* in_sizes, int n_in,
                              void* d_out, int out_size, void* d_ws, size_t ws_size,
                              hipStream_t stream) {
  (void)in_sizes; (void)n_in; (void)out_size; (void)ws_size;
  const float* ft1 = (const float*)d_in[0];
  const float* ft2 = (const float*)d_in[1];
  const float* ft3 = (const float*)d_in[2];
  const float* w1 = (const float*)d_in[3];
  const float* b1 = (const float*)d_in[4];
  const float* w2 = (const float*)d_in[5];
  const float* b2 = (const float*)d_in[6];
  const float* w3 = (const float*)d_in[7];
  const float* b3 = (const float*)d_in[8];
  const float* wd2 = (const float*)d_in[9];
  const float* wd3 = (const float*)d_in[10];
  const float* wf = (const float*)d_in[11];
  const float* bfu = (const float*)d_in[12];

  char* p = (char*)d_ws;
  half_t* xcat = (half_t*)p; p += (size_t)B_ * HW_ * 768 * 2;   // 50.3 MB
  half_t* h1 = (half_t*)p;   p += (size_t)B_ * HW_ * 256 * 2;   // 16.8 MB (reused as al2)
  half_t* h2 = (half_t*)p;   p += (size_t)B_ * HW_ * 256 * 2;   // 16.8 MB (reused as al3)
  float* off = (float*)p;    p += (size_t)B_ * HW_ * 36 * 4;    // 4.7 MB
  half_t* w1t = (half_t*)p;  p += (size_t)256 * 9 * 768 * 2;
  half_t* w2t = (half_t*)p;  p += (size_t)256 * 9 * 256 * 2;
  half_t* w3t = (half_t*)p;  p += (size_t)64 * 9 * 256 * 2;
  half_t* wd2t = (half_t*)p; p += (size_t)256 * 9 * 256 * 2;
  half_t* wd3t = (half_t*)p; p += (size_t)256 * 9 * 256 * 2;
  half_t* wft = (half_t*)p;  p += (size_t)256 * 768 * 2;        // total ~92 MiB
  half_t* al2 = h1;
  half_t* al3 = h2;

  pack_x<<<dim3(24 * B_ * H_), 256, 0, stream>>>(ft1, ft2, ft3, xcat);
  wtrans<<<6912, 256, 0, stream>>>(w1, w1t, 256, 256, 768);
  wtrans<<<2304, 256, 0, stream>>>(w2, w2t, 256, 256, 256);
  wtrans<<<576, 256, 0, stream>>>(w3, w3t, 36, 64, 256);
  wtrans<<<2304, 256, 0, stream>>>(wd2, wd2t, 256, 256, 256);
  wtrans<<<2304, 256, 0, stream>>>(wd3, wd3t, 256, 256, 256);
  castcopy<<<768, 256, 0, stream>>>(wf, wft, 256 * 768);

  conv3x3<768, true, false><<<dim3(B_ * H_, 4), 256, 0, stream>>>(xcat, w1t, b1, h1, nullptr, 256);
  conv3x3<256, true, false><<<dim3(B_ * H_, 4), 256, 0, stream>>>(h1, w2t, b2, h2, nullptr, 256);
  conv3x3<256, false, true><<<dim3(B_ * H_, 1), 256, 0, stream>>>(h2, w3t, b3, nullptr, off, 36);
  dcn<<<dim3(B_ * H_, 4), 256, 0, stream>>>(xcat, 256, off, 0, wd2t, al2);
  dcn<<<dim3(B_ * H_, 4), 256, 0, stream>>>(xcat, 512, off, 18, wd3t, al3);
  fuse1x1<<<dim3(B_ * H_, 4), 256, 0, stream>>>(xcat, al2, al3, wft, bfu, (float*)d_out);
}

// Round 2
// 488.376 us; speedup vs baseline: 1.6136x; 1.6136x over previous
//
#include <hip/hip_runtime.h>
#include <stdint.h>

#define H_ 128
#define W_ 128
#define HW_ 16384
#define B_ 2
#define XP_ 130  // padded spatial dim (1-px halo)

typedef __attribute__((ext_vector_type(4))) float f32x4;
typedef _Float16 half_t;
typedef __attribute__((ext_vector_type(8))) _Float16 h8v;
typedef __attribute__((ext_vector_type(4))) _Float16 h4v;

__device__ __forceinline__ f32x4 MFMA(h8v a, h8v b, f32x4 c) {
  return __builtin_amdgcn_mfma_f32_16x16x32_f16(a, b, c, 0, 0, 0);
}
__device__ __forceinline__ f32x4 zero4() {
  f32x4 z; z[0] = 0.f; z[1] = 0.f; z[2] = 0.f; z[3] = 0.f; return z;
}
// Swizzled LDS offset (element units). Tiles are [rows][64] fp16 (128B rows).
__device__ __forceinline__ int swz(int r, int c8) {
  return r * 64 + ((c8 ^ (r & 7)) << 3);
}

// global->LDS DMA, 16B per lane. Dest must be wave-uniform base + lane*16
// (our task = tid + it*256 guarantees this). Source is per-lane.
typedef const __attribute__((address_space(1))) uint32_t glb_u32;
typedef __attribute__((address_space(3))) uint32_t lds_u32;
__device__ __forceinline__ void gl_lds16(const half_t* g, half_t* l) {
  __builtin_amdgcn_global_load_lds((glb_u32*)(uintptr_t)g,
                                   (lds_u32*)(uint32_t)(uintptr_t)l, 16, 0, 0);
}

// ---------- zero the 1-px halo of a padded NHWC buffer ----------
__global__ __launch_bounds__(256) void zeropad(half_t* __restrict__ buf, int C) {
  int nc = C >> 3;
  int total = B_ * 516 * nc;
  int idx = blockIdx.x * 256 + threadIdx.x;
  if (idx >= total) return;
  int c8 = idx % nc;
  int p = idx / nc;
  int b = p / 516, i = p % 516;
  int y, x;
  if (i < 130) { y = 0; x = i; }
  else if (i < 260) { y = 129; x = i - 130; }
  else if (i < 388) { y = i - 260 + 1; x = 0; }
  else { y = i - 388 + 1; x = 129; }
  h8v z;
#pragma unroll
  for (int j = 0; j < 8; ++j) z[j] = (half_t)0.f;
  *(h8v*)(buf + ((size_t)(b * XP_ + y) * XP_ + x) * C + c8 * 8) = z;
}

// ---------- pack: three fp32 NCHW -> one fp16 padded NHWC (B,130,130,768) ----------
__global__ __launch_bounds__(256) void pack_x(
    const float* __restrict__ f1, const float* __restrict__ f2,
    const float* __restrict__ f3, half_t* __restrict__ xcat) {
  __shared__ float tile[64][65];
  int bid = blockIdx.x;
  int t = bid % 24, by = bid / 24;
  int b = by >> 7, y = by & 127;
  int s = t / 8, t2 = t % 8;
  int x0 = (t2 & 1) * 64, c0 = (t2 >> 1) * 64;
  const float* f = (s == 0) ? f1 : ((s == 1) ? f2 : f3);
  int tid = threadIdx.x;
  int rx = tid & 63, rc = tid >> 6;
  const float* srcp = f + ((size_t)(b * 256 + c0)) * HW_ + (size_t)y * W_ + x0;
#pragma unroll
  for (int i = 0; i < 16; ++i) {
    int c = rc + i * 4;
    tile[c][rx] = srcp[(size_t)c * HW_ + rx];
  }
  __syncthreads();
#pragma unroll
  for (int it = 0; it < 2; ++it) {
    int task = tid + it * 256;
    int x = task & 63, c8 = task >> 6;
    h8v v;
#pragma unroll
    for (int j = 0; j < 8; ++j) v[j] = (half_t)tile[c8 * 8 + j][x];
    size_t pix = (size_t)(b * XP_ + y + 1) * XP_ + x0 + x + 1;
    *(h8v*)(xcat + pix * 768 + s * 256 + c0 + c8 * 8) = v;
  }
}

// ---------- weight transform: OIHW fp32 -> pre-swizzled 16KB LDS tile images ----------
// Tile (coblk, t, cs): linear slot `task` (0..1023, 8 fp16 each) holds logical
// chunk c8 = (task&7)^(r&7) of row r = task>>3, so a linear DMA + swz() read works.
__global__ __launch_bounds__(256) void wtrans_swz(
    const float* __restrict__ w, half_t* __restrict__ wt,
    int CO, int CI) {
  int CS = CI >> 6;
  int idx = blockIdx.x * 256 + threadIdx.x;
  int e = idx & 8191, tile = idx >> 13;
  int task = e >> 3, j = e & 7;
  int r = task >> 3, c8 = (task & 7) ^ (r & 7);
  int cs = tile % CS;
  int rest = tile / CS;
  int t = rest % 9, coblk = rest / 9;
  int co = coblk * 128 + r;
  int ci = cs * 64 + c8 * 8 + j;
  float v = (co < CO) ? w[((size_t)co * CI + ci) * 9 + t] : 0.f;
  wt[idx] = (half_t)v;
}

// same for the 1x1 fuse weights: tiles (coblk, cs) over [256][768]
__global__ __launch_bounds__(256) void fuse_wswz(
    const float* __restrict__ w, half_t* __restrict__ wt) {
  int idx = blockIdx.x * 256 + threadIdx.x;  // total 2*12*8192
  int e = idx & 8191, tile = idx >> 13;
  int task = e >> 3, j = e & 7;
  int r = task >> 3, c8 = (task & 7) ^ (r & 7);
  int cs = tile % 12, coblk = tile / 12;
  int co = coblk * 128 + r;
  int ci = cs * 64 + c8 * 8 + j;
  wt[idx] = (half_t)w[(size_t)co * 768 + ci];
}

// ---------- 3x3 conv, implicit GEMM, padded NHWC fp16, DMA staging ----------
// Tile: 128co x 128px (one row). 4 waves as 2x2, each 64co x 64px, acc[4][4].
template <int CIN, bool RELU, bool FP32OUT>
__global__ __launch_bounds__(256) void conv3x3(
    const half_t* __restrict__ in, const half_t* __restrict__ wt,
    const float* __restrict__ bias, half_t* __restrict__ outb,
    float* __restrict__ outf, int COUT) {
  constexpr int CS = CIN / 64;
  __shared__ __align__(16) half_t wl[128 * 64];
  __shared__ __align__(16) half_t al[128 * 64];
  int tid = threadIdx.x;
  int by = blockIdx.x;
  int b = by >> 7, y = by & 127;
  int co0 = blockIdx.y * 128;
  int w = tid >> 6, l = tid & 63, lr = l & 15, lg = l >> 4;
  int wr = (w >> 1) * 64, wc = (w & 1) * 64;
  f32x4 acc[4][4];
#pragma unroll
  for (int i = 0; i < 4; ++i)
#pragma unroll
    for (int j = 0; j < 4; ++j) acc[i][j] = zero4();

  const half_t* wtp = wt + (size_t)blockIdx.y * (9 * CS) * 8192;
  for (int t = 0; t < 9; ++t) {
    int syp = y + t / 3;            // padded source row (sy-1+1)
    int kxo = t % 3 - 1;
    const half_t* arow = in + ((size_t)(b * XP_ + syp) * XP_ + 1 + kxo) * CIN;
    for (int cs = 0; cs < CS; ++cs) {
      __syncthreads();
#pragma unroll
      for (int it = 0; it < 4; ++it) {
        int task = tid + it * 256;
        gl_lds16(wtp + task * 8, wl + task * 8);
      }
#pragma unroll
      for (int it = 0; it < 4; ++it) {
        int task = tid + it * 256;
        int r = task >> 3, c8 = (task & 7) ^ (r & 7);
        gl_lds16(arow + (size_t)r * CIN + cs * 64 + c8 * 8, al + task * 8);
      }
      wtp += 8192;
      __syncthreads();  // drains vmcnt (DMA complete) + lgkmcnt
      h8v af[4][2], bf[4][2];
#pragma unroll
      for (int cg = 0; cg < 4; ++cg)
#pragma unroll
        for (int kc = 0; kc < 2; ++kc)
          af[cg][kc] = *(const h8v*)(wl + swz(wr + 16 * cg + lr, 4 * kc + lg));
#pragma unroll
      for (int pg = 0; pg < 4; ++pg)
#pragma unroll
        for (int kc = 0; kc < 2; ++kc)
          bf[pg][kc] = *(const h8v*)(al + swz(wc + 16 * pg + lr, 4 * kc + lg));
#pragma unroll
      for (int cg = 0; cg < 4; ++cg)
#pragma unroll
        for (int pg = 0; pg < 4; ++pg) {
          acc[cg][pg] = MFMA(af[cg][0], bf[pg][0], acc[cg][pg]);
          acc[cg][pg] = MFMA(af[cg][1], bf[pg][1], acc[cg][pg]);
        }
    }
  }
#pragma unroll
  for (int cg = 0; cg < 4; ++cg) {
    int co = co0 + wr + 16 * cg + 4 * lg;
    if (FP32OUT && co >= COUT) continue;
    f32x4 bv = *(const f32x4*)(bias + co);
#pragma unroll
    for (int pg = 0; pg < 4; ++pg) {
      int px = wc + 16 * pg + lr;
      f32x4 v = acc[cg][pg];
#pragma unroll
      for (int r = 0; r < 4; ++r) {
        v[r] += bv[r];
        if (RELU) v[r] = fmaxf(v[r], 0.f);
      }
      if (FP32OUT) {
        size_t pix = (size_t)(b * H_ + y) * W_ + px;
        *(f32x4*)(outf + pix * COUT + co) = v;
      } else {
        size_t pix = (size_t)(b * XP_ + y + 1) * XP_ + px + 1;
        h4v pv;
#pragma unroll
        for (int r = 0; r < 4; ++r) pv[r] = (half_t)v[r];
        *(h4v*)(outb + pix * 256 + co) = pv;
      }
    }
  }
}

// ---------- deformable conv: bilinear fused into GEMM, 128co x 128px ----------
__global__ __launch_bounds__(256) void dcn(
    const half_t* __restrict__ xcat, int cbase,
    const float* __restrict__ off, int obase,
    const half_t* __restrict__ wt, half_t* __restrict__ outb) {
  __shared__ __align__(16) half_t wl[128 * 64];
  __shared__ __align__(16) half_t al[128 * 64];
  __shared__ int caddr[128][4];
  __shared__ float cwt[128][4];
  int tid = threadIdx.x;
  int by = blockIdx.x;
  int b = by >> 7, y = by & 127;
  int co0 = blockIdx.y * 128;
  int w = tid >> 6, l = tid & 63, lr = l & 15, lg = l >> 4;
  int wr = (w >> 1) * 64, wc = (w & 1) * 64;
  size_t rowpix = (size_t)(b * H_ + y) * W_;
  f32x4 acc[4][4];
#pragma unroll
  for (int i = 0; i < 4; ++i)
#pragma unroll
    for (int j = 0; j < 4; ++j) acc[i][j] = zero4();

  const half_t* wtp = wt + (size_t)blockIdx.y * 36 * 8192;
  for (int t = 0; t < 9; ++t) {
    if (tid < 128) {
      int px = tid;
      const float* op = off + (rowpix + px) * 36 + obase + 2 * t;
      float dy = op[0], dx = op[1];
      float ysf = (float)(y + (t / 3) - 1) + dy;
      float xsf = (float)(px + (t % 3) - 1) + dx;
      float y0f = floorf(ysf), x0f = floorf(xsf);
      float fy = ysf - y0f, fx = xsf - x0f;
      int y0 = (int)y0f, x0 = (int)x0f;
#pragma unroll
      for (int c = 0; c < 4; ++c) {
        int iy = y0 + (c >> 1), ix = x0 + (c & 1);
        float wc2 = ((c >> 1) ? fy : 1.f - fy) * ((c & 1) ? fx : 1.f - fx);
        bool valid = (iy >= 0) && (iy < H_) && (ix >= 0) && (ix < W_);
        int cy = iy < 0 ? 0 : (iy > H_ - 1 ? H_ - 1 : iy);
        int cx = ix < 0 ? 0 : (ix > W_ - 1 ? W_ - 1 : ix);
        caddr[px][c] = ((b * XP_ + cy + 1) * XP_ + cx + 1) * 768 + cbase;
        cwt[px][c] = valid ? wc2 : 0.f;
      }
    }
    for (int cs = 0; cs < 4; ++cs) {
      int c0 = cs * 64;
      __syncthreads();  // orders coeff writes vs staging reads; LDS reuse
#pragma unroll
      for (int it = 0; it < 4; ++it) {
        int task = tid + it * 256;
        gl_lds16(wtp + task * 8, wl + task * 8);
      }
#pragma unroll
      for (int it = 0; it < 4; ++it) {
        int task = tid + it * 256;
        int px = task >> 3, c8 = task & 7;
        int cc = c0 + c8 * 8;
        float av[8];
#pragma unroll
        for (int j = 0; j < 8; ++j) av[j] = 0.f;
#pragma unroll
        for (int c = 0; c < 4; ++c) {
          float wcf = cwt[px][c];
          h8v v = *(const h8v*)(xcat + caddr[px][c] + cc);
#pragma unroll
          for (int j = 0; j < 8; ++j) av[j] += wcf * (float)v[j];
        }
        h8v pv;
#pragma unroll
        for (int j = 0; j < 8; ++j) pv[j] = (half_t)av[j];
        *(h8v*)(al + swz(px, c8)) = pv;
      }
      wtp += 8192;
      __syncthreads();
      h8v af[4][2], bf[4][2];
#pragma unroll
      for (int cg = 0; cg < 4; ++cg)
#pragma unroll
        for (int kc = 0; kc < 2; ++kc)
          af[cg][kc] = *(const h8v*)(wl + swz(wr + 16 * cg + lr, 4 * kc + lg));
#pragma unroll
      for (int pg = 0; pg < 4; ++pg)
#pragma unroll
        for (int kc = 0; kc < 2; ++kc)
          bf[pg][kc] = *(const h8v*)(al + swz(wc + 16 * pg + lr, 4 * kc + lg));
#pragma unroll
      for (int cg = 0; cg < 4; ++cg)
#pragma unroll
        for (int pg = 0; pg < 4; ++pg) {
          acc[cg][pg] = MFMA(af[cg][0], bf[pg][0], acc[cg][pg]);
          acc[cg][pg] = MFMA(af[cg][1], bf[pg][1], acc[cg][pg]);
        }
    }
  }
#pragma unroll
  for (int cg = 0; cg < 4; ++cg) {
    int co = co0 + wr + 16 * cg + 4 * lg;
#pragma unroll
    for (int pg = 0; pg < 4; ++pg) {
      int px = wc + 16 * pg + lr;
      size_t pix = rowpix + px;
      f32x4 v = acc[cg][pg];
      h4v pv;
#pragma unroll
      for (int r = 0; r < 4; ++r) pv[r] = (half_t)v[r];
      *(h4v*)(outb + pix * 256 + co) = pv;
    }
  }
}

// ---------- 1x1 fuse conv: fully DMA-staged, out fp32 NCHW ----------
__global__ __launch_bounds__(256) void fuse1x1(
    const half_t* __restrict__ xcat, const half_t* __restrict__ al2,
    const half_t* __restrict__ al3, const half_t* __restrict__ wt,
    const float* __restrict__ bias, float* __restrict__ out) {
  __shared__ __align__(16) half_t wl[128 * 64];
  __shared__ __align__(16) half_t al[128 * 64];
  int tid = threadIdx.x;
  int by = blockIdx.x;
  int b = by >> 7, y = by & 127;
  int co0 = blockIdx.y * 128;
  int w = tid >> 6, l = tid & 63, lr = l & 15, lg = l >> 4;
  int pxb = (w >> 1) * 64, cob = (w & 1) * 64;
  f32x4 acc[4][4];  // [pg][cg]
#pragma unroll
  for (int i = 0; i < 4; ++i)
#pragma unroll
    for (int j = 0; j < 4; ++j) acc[i][j] = zero4();

  const half_t* wtp = wt + (size_t)blockIdx.y * 12 * 8192;
  size_t rowpix = (size_t)(b * H_ + y) * W_;
  const half_t* xrow = xcat + ((size_t)(b * XP_ + y + 1) * XP_ + 1) * 768;
  for (int cs = 0; cs < 12; ++cs) {
    __syncthreads();
#pragma unroll
    for (int it = 0; it < 4; ++it) {
      int task = tid + it * 256;
      gl_lds16(wtp + task * 8, wl + task * 8);
    }
#pragma unroll
    for (int it = 0; it < 4; ++it) {
      int task = tid + it * 256;
      int r = task >> 3, c8 = (task & 7) ^ (r & 7);
      int kk = cs * 64 + c8 * 8;
      const half_t* sp;
      if (kk < 256) sp = xrow + (size_t)r * 768 + kk;
      else if (kk < 512) sp = al2 + (rowpix + r) * 256 + (kk - 256);
      else sp = al3 + (rowpix + r) * 256 + (kk - 512);
      gl_lds16(sp, al + task * 8);
    }
    wtp += 8192;
    __syncthreads();
    h8v af[4][2], bf[4][2];
#pragma unroll
    for (int pg = 0; pg < 4; ++pg)
#pragma unroll
      for (int kc = 0; kc < 2; ++kc)
        af[pg][kc] = *(const h8v*)(al + swz(pxb + 16 * pg + lr, 4 * kc + lg));
#pragma unroll
    for (int cg = 0; cg < 4; ++cg)
#pragma unroll
      for (int kc = 0; kc < 2; ++kc)
        bf[cg][kc] = *(const h8v*)(wl + swz(cob + 16 * cg + lr, 4 * kc + lg));
#pragma unroll
    for (int pg = 0; pg < 4; ++pg)
#pragma unroll
      for (int cg = 0; cg < 4; ++cg) {
        acc[pg][cg] = MFMA(af[pg][0], bf[cg][0], acc[pg][cg]);
        acc[pg][cg] = MFMA(af[pg][1], bf[cg][1], acc[pg][cg]);
      }
  }
#pragma unroll
  for (int pg = 0; pg < 4; ++pg)
#pragma unroll
    for (int cg = 0; cg < 4; ++cg) {
      int px = pxb + 16 * pg + 4 * lg;
      int co = co0 + cob + 16 * cg + lr;
      float bb = bias[co];
      f32x4 v = acc[pg][cg];
#pragma unroll
      for (int r = 0; r < 4; ++r) v[r] += bb;
      *(f32x4*)(out + ((size_t)(b * 256 + co)) * HW_ + (size_t)y * W_ + px) = v;
    }
}

extern "C" void kernel_launch(void* const* d_in, const int* in_sizes, int n_in,
                              void* d_out, int out_size, void* d_ws, size_t ws_size,
                              hipStream_t stream) {
  (void)in_sizes; (void)n_in; (void)out_size; (void)ws_size;
  const float* ft1 = (const float*)d_in[0];
  const float* ft2 = (const float*)d_in[1];
  const float* ft3 = (const float*)d_in[2];
  const float* w1 = (const float*)d_in[3];
  const float* b1 = (const float*)d_in[4];
  const float* w2 = (const float*)d_in[5];
  const float* b2 = (const float*)d_in[6];
  const float* w3 = (const float*)d_in[7];
  const float* b3 = (const float*)d_in[8];
  const float* wd2 = (const float*)d_in[9];
  const float* wd3 = (const float*)d_in[10];
  const float* wf = (const float*)d_in[11];
  const float* bfu = (const float*)d_in[12];

  char* p = (char*)d_ws;
  half_t* xcat = (half_t*)p; p += (size_t)B_ * XP_ * XP_ * 768 * 2;  // 51.9 MB
  half_t* h1p = (half_t*)p;  p += (size_t)B_ * XP_ * XP_ * 256 * 2;  // 17.3 MB
  half_t* h2p = (half_t*)p;  p += (size_t)B_ * XP_ * XP_ * 256 * 2;  // 17.3 MB
  float* off = (float*)p;    p += (size_t)B_ * HW_ * 36 * 4;         // 4.7 MB
  half_t* w1t = (half_t*)p;  p += (size_t)2 * 9 * 12 * 8192 * 2;
  half_t* w2t = (half_t*)p;  p += (size_t)2 * 9 * 4 * 8192 * 2;
  half_t* w3t = (half_t*)p;  p += (size_t)1 * 9 * 4 * 8192 * 2;
  half_t* wd2t = (half_t*)p; p += (size_t)2 * 9 * 4 * 8192 * 2;
  half_t* wd3t = (half_t*)p; p += (size_t)2 * 9 * 4 * 8192 * 2;
  half_t* wft = (half_t*)p;  p += (size_t)2 * 12 * 8192 * 2;         // ~99.5 MB total
  half_t* al2 = h1p;  // h1p dead after conv2; al2 (16.8MB) fits in its 17.3MB
  half_t* al3 = h2p;  // h2p dead after conv3

  int zp768 = (B_ * 516 * 96 + 255) / 256;
  int zp256 = (B_ * 516 * 32 + 255) / 256;
  zeropad<<<zp768, 256, 0, stream>>>(xcat, 768);
  zeropad<<<zp256, 256, 0, stream>>>(h1p, 256);
  zeropad<<<zp256, 256, 0, stream>>>(h2p, 256);
  pack_x<<<24 * B_ * H_, 256, 0, stream>>>(ft1, ft2, ft3, xcat);
  wtrans_swz<<<6912, 256, 0, stream>>>(w1, w1t, 256, 768);
  wtrans_swz<<<2304, 256, 0, stream>>>(w2, w2t, 256, 256);
  wtrans_swz<<<1152, 256, 0, stream>>>(w3, w3t, 36, 256);
  wtrans_swz<<<2304, 256, 0, stream>>>(wd2, wd2t, 256, 256);
  wtrans_swz<<<2304, 256, 0, stream>>>(wd3, wd3t, 256, 256);
  fuse_wswz<<<768, 256, 0, stream>>>(wf, wft);

  conv3x3<768, true, false><<<dim3(B_ * H_, 2), 256, 0, stream>>>(xcat, w1t, b1, h1p, nullptr, 256);
  conv3x3<256, true, false><<<dim3(B_ * H_, 2), 256, 0, stream>>>(h1p, w2t, b2, h2p, nullptr, 256);
  conv3x3<256, false, true><<<dim3(B_ * H_, 1), 256, 0, stream>>>(h2p, w3t, b3, nullptr, off, 36);
  dcn<<<dim3(B_ * H_, 2), 256, 0, stream>>>(xcat, 256, off, 0, wd2t, al2);
  dcn<<<dim3(B_ * H_, 2), 256, 0, stream>>>(xcat, 512, off, 18, wd3t, al3);
  fuse1x1<<<dim3(B_ * H_, 2), 256, 0, stream>>>(xcat, al2, al3, wft, bfu, (float*)d_out);
}

// Round 3
// 447.472 us; speedup vs baseline: 1.7611x; 1.0914x over previous
//
#include <hip/hip_runtime.h>
#include <stdint.h>

#define H_ 128
#define W_ 128
#define HW_ 16384
#define B_ 2
#define XP_ 130  // padded spatial dim (1-px halo)

typedef __attribute__((ext_vector_type(4))) float f32x4;
typedef _Float16 half_t;
typedef __attribute__((ext_vector_type(8))) _Float16 h8v;
typedef __attribute__((ext_vector_type(4))) _Float16 h4v;

__device__ __forceinline__ f32x4 MFMA(h8v a, h8v b, f32x4 c) {
  return __builtin_amdgcn_mfma_f32_16x16x32_f16(a, b, c, 0, 0, 0);
}
__device__ __forceinline__ f32x4 zero4() {
  f32x4 z; z[0] = 0.f; z[1] = 0.f; z[2] = 0.f; z[3] = 0.f; return z;
}
// Swizzled LDS offset (element units). Tiles are [rows][64] fp16 (128B rows).
__device__ __forceinline__ int swz(int r, int c8) {
  return r * 64 + ((c8 ^ (r & 7)) << 3);
}
// XCD-aware row swizzle: 256 rows, 8 XCDs, 32 contiguous rows per XCD.
__device__ __forceinline__ int xcd_row(int bx) {
  return ((bx & 7) << 5) | (bx >> 3);
}

// global->LDS DMA, 16B per lane. Dest must be wave-uniform base + lane*16.
typedef const __attribute__((address_space(1))) uint32_t glb_u32;
typedef __attribute__((address_space(3))) uint32_t lds_u32;
__device__ __forceinline__ void gl_lds16(const half_t* g, half_t* l) {
  __builtin_amdgcn_global_load_lds((glb_u32*)(uintptr_t)g,
                                   (lds_u32*)(uint32_t)(uintptr_t)l, 16, 0, 0);
}

// ---------- zero the 1-px halo of a padded NHWC buffer ----------
__global__ __launch_bounds__(256) void zeropad(half_t* __restrict__ buf, int C) {
  int nc = C >> 3;
  int total = B_ * 516 * nc;
  int idx = blockIdx.x * 256 + threadIdx.x;
  if (idx >= total) return;
  int c8 = idx % nc;
  int p = idx / nc;
  int b = p / 516, i = p % 516;
  int y, x;
  if (i < 130) { y = 0; x = i; }
  else if (i < 260) { y = 129; x = i - 130; }
  else if (i < 388) { y = i - 260 + 1; x = 0; }
  else { y = i - 388 + 1; x = 129; }
  h8v z;
#pragma unroll
  for (int j = 0; j < 8; ++j) z[j] = (half_t)0.f;
  *(h8v*)(buf + ((size_t)(b * XP_ + y) * XP_ + x) * C + c8 * 8) = z;
}

// ---------- pack: three fp32 NCHW -> one fp16 padded NHWC (B,130,130,768) ----------
__global__ __launch_bounds__(256) void pack_x(
    const float* __restrict__ f1, const float* __restrict__ f2,
    const float* __restrict__ f3, half_t* __restrict__ xcat) {
  __shared__ float tile[64][65];
  int bid = blockIdx.x;
  int t = bid % 24, by = bid / 24;
  int b = by >> 7, y = by & 127;
  int s = t / 8, t2 = t % 8;
  int x0 = (t2 & 1) * 64, c0 = (t2 >> 1) * 64;
  const float* f = (s == 0) ? f1 : ((s == 1) ? f2 : f3);
  int tid = threadIdx.x;
  int rx = tid & 63, rc = tid >> 6;
  const float* srcp = f + ((size_t)(b * 256 + c0)) * HW_ + (size_t)y * W_ + x0;
#pragma unroll
  for (int i = 0; i < 16; ++i) {
    int c = rc + i * 4;
    tile[c][rx] = srcp[(size_t)c * HW_ + rx];
  }
  __syncthreads();
#pragma unroll
  for (int it = 0; it < 2; ++it) {
    int task = tid + it * 256;
    int x = task & 63, c8 = task >> 6;
    h8v v;
#pragma unroll
    for (int j = 0; j < 8; ++j) v[j] = (half_t)tile[c8 * 8 + j][x];
    size_t pix = (size_t)(b * XP_ + y + 1) * XP_ + x0 + x + 1;
    *(h8v*)(xcat + pix * 768 + s * 256 + c0 + c8 * 8) = v;
  }
}

// ---------- weight transform: OIHW fp32 -> pre-swizzled 16KB LDS tile images ----------
__global__ __launch_bounds__(256) void wtrans_swz(
    const float* __restrict__ w, half_t* __restrict__ wt,
    int CO, int CI) {
  int CS = CI >> 6;
  int idx = blockIdx.x * 256 + threadIdx.x;
  int e = idx & 8191, tile = idx >> 13;
  int task = e >> 3, j = e & 7;
  int r = task >> 3, c8 = (task & 7) ^ (r & 7);
  int cs = tile % CS;
  int rest = tile / CS;
  int t = rest % 9, coblk = rest / 9;
  int co = coblk * 128 + r;
  int ci = cs * 64 + c8 * 8 + j;
  float v = (co < CO) ? w[((size_t)co * CI + ci) * 9 + t] : 0.f;
  wt[idx] = (half_t)v;
}

__global__ __launch_bounds__(256) void fuse_wswz(
    const float* __restrict__ w, half_t* __restrict__ wt) {
  int idx = blockIdx.x * 256 + threadIdx.x;  // total 2*12*8192
  int e = idx & 8191, tile = idx >> 13;
  int task = e >> 3, j = e & 7;
  int r = task >> 3, c8 = (task & 7) ^ (r & 7);
  int cs = tile % 12, coblk = tile / 12;
  int co = coblk * 128 + r;
  int ci = cs * 64 + c8 * 8 + j;
  wt[idx] = (half_t)w[(size_t)co * 768 + ci];
}

// ---------- 3x3 conv, implicit GEMM, 2-phase double-buffered pipeline ----------
// Tile: 128co x 128px (one row). 4 waves as 2x2, each 64co x 64px, acc[4][4].
template <int CIN, bool RELU, bool FP32OUT>
__global__ __launch_bounds__(256) void conv3x3(
    const half_t* __restrict__ in, const half_t* __restrict__ wt,
    const float* __restrict__ bias, half_t* __restrict__ outb,
    float* __restrict__ outf, int COUT) {
  constexpr int CS = CIN / 64;
  constexpr int NS = 9 * CS;
  __shared__ __align__(16) half_t wl[2][8192];
  __shared__ __align__(16) half_t al[2][8192];
  int tid = threadIdx.x;
  int by = xcd_row(blockIdx.x);
  int b = by >> 7, y = by & 127;
  int co0 = blockIdx.y * 128;
  int w = tid >> 6, l = tid & 63, lr = l & 15, lg = l >> 4;
  int wr = (w >> 1) * 64, wc = (w & 1) * 64;
  f32x4 acc[4][4];
#pragma unroll
  for (int i = 0; i < 4; ++i)
#pragma unroll
    for (int j = 0; j < 4; ++j) acc[i][j] = zero4();

  const half_t* wbase = wt + (size_t)blockIdx.y * NS * 8192;

  auto stage = [&](int s, int buf) {
    const half_t* wp = wbase + (size_t)s * 8192;
#pragma unroll
    for (int it = 0; it < 4; ++it) {
      int task = tid + it * 256;
      gl_lds16(wp + task * 8, &wl[buf][task * 8]);
    }
    int t = s / CS, cs = s % CS;
    int syp = y + t / 3, kxo = t % 3 - 1;
    const half_t* arow = in + ((size_t)(b * XP_ + syp) * XP_ + 1 + kxo) * CIN + cs * 64;
#pragma unroll
    for (int it = 0; it < 4; ++it) {
      int task = tid + it * 256;
      int r = task >> 3, c8 = (task & 7) ^ (r & 7);
      gl_lds16(arow + (size_t)r * CIN + c8 * 8, &al[buf][task * 8]);
    }
  };

  stage(0, 0);
  __syncthreads();
  for (int s = 0; s < NS; ++s) {
    int cur = s & 1;
    if (s + 1 < NS) stage(s + 1, cur ^ 1);
    const half_t* wb = wl[cur];
    const half_t* ab = al[cur];
    h8v af[4][2], bf[4][2];
#pragma unroll
    for (int cg = 0; cg < 4; ++cg)
#pragma unroll
      for (int kc = 0; kc < 2; ++kc)
        af[cg][kc] = *(const h8v*)(wb + swz(wr + 16 * cg + lr, 4 * kc + lg));
#pragma unroll
    for (int pg = 0; pg < 4; ++pg)
#pragma unroll
      for (int kc = 0; kc < 2; ++kc)
        bf[pg][kc] = *(const h8v*)(ab + swz(wc + 16 * pg + lr, 4 * kc + lg));
#pragma unroll
    for (int cg = 0; cg < 4; ++cg)
#pragma unroll
      for (int pg = 0; pg < 4; ++pg) {
        acc[cg][pg] = MFMA(af[cg][0], bf[pg][0], acc[cg][pg]);
        acc[cg][pg] = MFMA(af[cg][1], bf[pg][1], acc[cg][pg]);
      }
    __syncthreads();
  }
#pragma unroll
  for (int cg = 0; cg < 4; ++cg) {
    int co = co0 + wr + 16 * cg + 4 * lg;
    if (FP32OUT && co >= COUT) continue;
    f32x4 bv = *(const f32x4*)(bias + co);
#pragma unroll
    for (int pg = 0; pg < 4; ++pg) {
      int px = wc + 16 * pg + lr;
      f32x4 v = acc[cg][pg];
#pragma unroll
      for (int r = 0; r < 4; ++r) {
        v[r] += bv[r];
        if (RELU) v[r] = fmaxf(v[r], 0.f);
      }
      if (FP32OUT) {
        size_t pix = (size_t)(b * H_ + y) * W_ + px;
        *(f32x4*)(outf + pix * COUT + co) = v;
      } else {
        size_t pix = (size_t)(b * XP_ + y + 1) * XP_ + px + 1;
        h4v pv;
#pragma unroll
        for (int r = 0; r < 4; ++r) pv[r] = (half_t)v[r];
        *(h4v*)(outb + pix * 256 + co) = pv;
      }
    }
  }
}

// ---------- deformable conv: 2-phase pipeline + T14 split bilinear staging ----------
__global__ __launch_bounds__(256) void dcn(
    const half_t* __restrict__ xcat, int cbase,
    const float* __restrict__ off, int obase,
    const half_t* __restrict__ wt, half_t* __restrict__ outb) {
  __shared__ __align__(16) half_t wl[2][8192];
  __shared__ __align__(16) half_t al[2][8192];
  __shared__ int caddr[2][128][4];
  __shared__ float cwt[2][128][4];
  int tid = threadIdx.x;
  int by = xcd_row(blockIdx.x);
  int b = by >> 7, y = by & 127;
  int co0 = blockIdx.y * 128;
  int w = tid >> 6, l = tid & 63, lr = l & 15, lg = l >> 4;
  int wr = (w >> 1) * 64, wc = (w & 1) * 64;
  size_t rowpix = (size_t)(b * H_ + y) * W_;
  f32x4 acc[4][4];
#pragma unroll
  for (int i = 0; i < 4; ++i)
#pragma unroll
    for (int j = 0; j < 4; ++j) acc[i][j] = zero4();

  const half_t* wbase = wt + (size_t)blockIdx.y * 36 * 8192;

  auto coeffs = [&](int t) {  // writes coeff buffer [t&1]; caller barriers
    if (tid < 128) {
      int px = tid;
      const float* op = off + (rowpix + px) * 36 + obase + 2 * t;
      float dy = op[0], dx = op[1];
      float ysf = (float)(y + (t / 3) - 1) + dy;
      float xsf = (float)(px + (t % 3) - 1) + dx;
      float y0f = floorf(ysf), x0f = floorf(xsf);
      float fy = ysf - y0f, fx = xsf - x0f;
      int y0 = (int)y0f, x0 = (int)x0f;
#pragma unroll
      for (int c = 0; c < 4; ++c) {
        int iy = y0 + (c >> 1), ix = x0 + (c & 1);
        float wc2 = ((c >> 1) ? fy : 1.f - fy) * ((c & 1) ? fx : 1.f - fx);
        bool valid = (iy >= 0) && (iy < H_) && (ix >= 0) && (ix < W_);
        int cy = iy < 0 ? 0 : (iy > H_ - 1 ? H_ - 1 : iy);
        int cx = ix < 0 ? 0 : (ix > W_ - 1 ? W_ - 1 : ix);
        caddr[t & 1][px][c] = ((b * XP_ + cy + 1) * XP_ + cx + 1) * 768 + cbase;
        cwt[t & 1][px][c] = valid ? wc2 : 0.f;
      }
    }
  };

  h8v cv[4][4];  // prefetched corner values for the NEXT step (all-static idx)
  auto blendload = [&](int s) {
    int t = (s >> 2) & 1;
    int c0 = (s & 3) * 64;
#pragma unroll
    for (int it = 0; it < 4; ++it) {
      int task = tid + it * 256;
      int px = task >> 3, c8 = task & 7;
      int cc = c0 + c8 * 8;
#pragma unroll
      for (int c = 0; c < 4; ++c)
        cv[it][c] = *(const h8v*)(xcat + caddr[t][px][c] + cc);
    }
  };
  auto blendwrite = [&](int s, int buf) {
    int t = (s >> 2) & 1;
#pragma unroll
    for (int it = 0; it < 4; ++it) {
      int task = tid + it * 256;
      int px = task >> 3, c8 = task & 7;
      float av[8];
#pragma unroll
      for (int j = 0; j < 8; ++j) av[j] = 0.f;
#pragma unroll
      for (int c = 0; c < 4; ++c) {
        float wcf = cwt[t][px][c];
#pragma unroll
        for (int j = 0; j < 8; ++j) av[j] += wcf * (float)cv[it][c][j];
      }
      h8v pv;
#pragma unroll
      for (int j = 0; j < 8; ++j) pv[j] = (half_t)av[j];
      *(h8v*)(&al[buf][swz(px, c8)]) = pv;
    }
  };
  auto stagew = [&](int s, int buf) {
    const half_t* wp = wbase + (size_t)s * 8192;
#pragma unroll
    for (int it = 0; it < 4; ++it) {
      int task = tid + it * 256;
      gl_lds16(wp + task * 8, &wl[buf][task * 8]);
    }
  };

  coeffs(0);
  __syncthreads();
  stagew(0, 0);
  blendload(0);
  blendwrite(0, 0);
  __syncthreads();
  for (int s = 0; s < 36; ++s) {
    int cur = s & 1, nxt = cur ^ 1;
    if (s + 1 < 36) {
      stagew(s + 1, nxt);   // DMA in flight across the MFMAs
      blendload(s + 1);     // corner loads in flight across the MFMAs
    }
    if ((s & 3) == 0 && (s >> 2) + 1 < 9) coeffs((s >> 2) + 1);  // other parity buf
    const half_t* wb = wl[cur];
    const half_t* ab = al[cur];
    h8v af[4][2], bf[4][2];
#pragma unroll
    for (int cg = 0; cg < 4; ++cg)
#pragma unroll
      for (int kc = 0; kc < 2; ++kc)
        af[cg][kc] = *(const h8v*)(wb + swz(wr + 16 * cg + lr, 4 * kc + lg));
#pragma unroll
    for (int pg = 0; pg < 4; ++pg)
#pragma unroll
      for (int kc = 0; kc < 2; ++kc)
        bf[pg][kc] = *(const h8v*)(ab + swz(wc + 16 * pg + lr, 4 * kc + lg));
#pragma unroll
    for (int cg = 0; cg < 4; ++cg)
#pragma unroll
      for (int pg = 0; pg < 4; ++pg) {
        acc[cg][pg] = MFMA(af[cg][0], bf[pg][0], acc[cg][pg]);
        acc[cg][pg] = MFMA(af[cg][1], bf[pg][1], acc[cg][pg]);
      }
    if (s + 1 < 36) blendwrite(s + 1, nxt);
    __syncthreads();
  }
#pragma unroll
  for (int cg = 0; cg < 4; ++cg) {
    int co = co0 + wr + 16 * cg + 4 * lg;
#pragma unroll
    for (int pg = 0; pg < 4; ++pg) {
      int px = wc + 16 * pg + lr;
      size_t pix = rowpix + px;
      f32x4 v = acc[cg][pg];
      h4v pv;
#pragma unroll
      for (int r = 0; r < 4; ++r) pv[r] = (half_t)v[r];
      *(h4v*)(outb + pix * 256 + co) = pv;
    }
  }
}

// ---------- 1x1 fuse conv: 2-phase, fully DMA-staged, out fp32 NCHW ----------
__global__ __launch_bounds__(256) void fuse1x1(
    const half_t* __restrict__ xcat, const half_t* __restrict__ al2,
    const half_t* __restrict__ al3, const half_t* __restrict__ wt,
    const float* __restrict__ bias, float* __restrict__ out) {
  __shared__ __align__(16) half_t wl[2][8192];
  __shared__ __align__(16) half_t al[2][8192];
  int tid = threadIdx.x;
  int by = blockIdx.x;
  int b = by >> 7, y = by & 127;
  int co0 = blockIdx.y * 128;
  int w = tid >> 6, l = tid & 63, lr = l & 15, lg = l >> 4;
  int pxb = (w >> 1) * 64, cob = (w & 1) * 64;
  f32x4 acc[4][4];  // [pg][cg]
#pragma unroll
  for (int i = 0; i < 4; ++i)
#pragma unroll
    for (int j = 0; j < 4; ++j) acc[i][j] = zero4();

  const half_t* wbase = wt + (size_t)blockIdx.y * 12 * 8192;
  size_t rowpix = (size_t)(b * H_ + y) * W_;
  const half_t* xrow = xcat + ((size_t)(b * XP_ + y + 1) * XP_ + 1) * 768;

  auto stage = [&](int cs, int buf) {
    const half_t* wp = wbase + (size_t)cs * 8192;
#pragma unroll
    for (int it = 0; it < 4; ++it) {
      int task = tid + it * 256;
      gl_lds16(wp + task * 8, &wl[buf][task * 8]);
    }
#pragma unroll
    for (int it = 0; it < 4; ++it) {
      int task = tid + it * 256;
      int r = task >> 3, c8 = (task & 7) ^ (r & 7);
      int kk = cs * 64 + c8 * 8;
      const half_t* sp;
      if (kk < 256) sp = xrow + (size_t)r * 768 + kk;
      else if (kk < 512) sp = al2 + (rowpix + r) * 256 + (kk - 256);
      else sp = al3 + (rowpix + r) * 256 + (kk - 512);
      gl_lds16(sp, &al[buf][task * 8]);
    }
  };

  stage(0, 0);
  __syncthreads();
  for (int cs = 0; cs < 12; ++cs) {
    int cur = cs & 1;
    if (cs + 1 < 12) stage(cs + 1, cur ^ 1);
    const half_t* wb = wl[cur];
    const half_t* ab = al[cur];
    h8v af[4][2], bf[4][2];
#pragma unroll
    for (int pg = 0; pg < 4; ++pg)
#pragma unroll
      for (int kc = 0; kc < 2; ++kc)
        af[pg][kc] = *(const h8v*)(ab + swz(pxb + 16 * pg + lr, 4 * kc + lg));
#pragma unroll
    for (int cg = 0; cg < 4; ++cg)
#pragma unroll
      for (int kc = 0; kc < 2; ++kc)
        bf[cg][kc] = *(const h8v*)(wb + swz(cob + 16 * cg + lr, 4 * kc + lg));
#pragma unroll
    for (int pg = 0; pg < 4; ++pg)
#pragma unroll
      for (int cg = 0; cg < 4; ++cg) {
        acc[pg][cg] = MFMA(af[pg][0], bf[cg][0], acc[pg][cg]);
        acc[pg][cg] = MFMA(af[pg][1], bf[cg][1], acc[pg][cg]);
      }
    __syncthreads();
  }
#pragma unroll
  for (int pg = 0; pg < 4; ++pg)
#pragma unroll
    for (int cg = 0; cg < 4; ++cg) {
      int px = pxb + 16 * pg + 4 * lg;
      int co = co0 + cob + 16 * cg + lr;
      float bb = bias[co];
      f32x4 v = acc[pg][cg];
#pragma unroll
      for (int r = 0; r < 4; ++r) v[r] += bb;
      *(f32x4*)(out + ((size_t)(b * 256 + co)) * HW_ + (size_t)y * W_ + px) = v;
    }
}

extern "C" void kernel_launch(void* const* d_in, const int* in_sizes, int n_in,
                              void* d_out, int out_size, void* d_ws, size_t ws_size,
                              hipStream_t stream) {
  (void)in_sizes; (void)n_in; (void)out_size; (void)ws_size;
  const float* ft1 = (const float*)d_in[0];
  const float* ft2 = (const float*)d_in[1];
  const float* ft3 = (const float*)d_in[2];
  const float* w1 = (const float*)d_in[3];
  const float* b1 = (const float*)d_in[4];
  const float* w2 = (const float*)d_in[5];
  const float* b2 = (const float*)d_in[6];
  const float* w3 = (const float*)d_in[7];
  const float* b3 = (const float*)d_in[8];
  const float* wd2 = (const float*)d_in[9];
  const float* wd3 = (const float*)d_in[10];
  const float* wf = (const float*)d_in[11];
  const float* bfu = (const float*)d_in[12];

  char* p = (char*)d_ws;
  half_t* xcat = (half_t*)p; p += (size_t)B_ * XP_ * XP_ * 768 * 2;  // 51.9 MB
  half_t* h1p = (half_t*)p;  p += (size_t)B_ * XP_ * XP_ * 256 * 2;  // 17.3 MB
  half_t* h2p = (half_t*)p;  p += (size_t)B_ * XP_ * XP_ * 256 * 2;  // 17.3 MB
  float* off = (float*)p;    p += (size_t)B_ * HW_ * 36 * 4;         // 4.7 MB
  half_t* w1t = (half_t*)p;  p += (size_t)2 * 9 * 12 * 8192 * 2;
  half_t* w2t = (half_t*)p;  p += (size_t)2 * 9 * 4 * 8192 * 2;
  half_t* w3t = (half_t*)p;  p += (size_t)1 * 9 * 4 * 8192 * 2;
  half_t* wd2t = (half_t*)p; p += (size_t)2 * 9 * 4 * 8192 * 2;
  half_t* wd3t = (half_t*)p; p += (size_t)2 * 9 * 4 * 8192 * 2;
  half_t* wft = (half_t*)p;  p += (size_t)2 * 12 * 8192 * 2;         // ~99.5 MB total
  half_t* al2 = h1p;  // h1p dead after conv2
  half_t* al3 = h2p;  // h2p dead after conv3

  int zp768 = (B_ * 516 * 96 + 255) / 256;
  int zp256 = (B_ * 516 * 32 + 255) / 256;
  zeropad<<<zp768, 256, 0, stream>>>(xcat, 768);
  zeropad<<<zp256, 256, 0, stream>>>(h1p, 256);
  zeropad<<<zp256, 256, 0, stream>>>(h2p, 256);
  pack_x<<<24 * B_ * H_, 256, 0, stream>>>(ft1, ft2, ft3, xcat);
  wtrans_swz<<<6912, 256, 0, stream>>>(w1, w1t, 256, 768);
  wtrans_swz<<<2304, 256, 0, stream>>>(w2, w2t, 256, 256);
  wtrans_swz<<<1152, 256, 0, stream>>>(w3, w3t, 36, 256);
  wtrans_swz<<<2304, 256, 0, stream>>>(wd2, wd2t, 256, 256);
  wtrans_swz<<<2304, 256, 0, stream>>>(wd3, wd3t, 256, 256);
  fuse_wswz<<<768, 256, 0, stream>>>(wf, wft);

  conv3x3<768, true, false><<<dim3(B_ * H_, 2), 256, 0, stream>>>(xcat, w1t, b1, h1p, nullptr, 256);
  conv3x3<256, true, false><<<dim3(B_ * H_, 2), 256, 0, stream>>>(h1p, w2t, b2, h2p, nullptr, 256);
  conv3x3<256, false, true><<<dim3(B_ * H_, 1), 256, 0, stream>>>(h2p, w3t, b3, nullptr, off, 36);
  dcn<<<dim3(B_ * H_, 2), 256, 0, stream>>>(xcat, 256, off, 0, wd2t, al2);
  dcn<<<dim3(B_ * H_, 2), 256, 0, stream>>>(xcat, 512, off, 18, wd3t, al3);
  fuse1x1<<<dim3(B_ * H_, 2), 256, 0, stream>>>(xcat, al2, al3, wft, bfu, (float*)d_out);
}